// Round 5
// baseline (36912.592 us; speedup 1.0000x reference)
//
#include <hip/hip_runtime.h>

#define DM     512
#define LAT    128
#define WIN_   256
#define ENC    55
#define GB     32        // batch groups
#define BT     8         // batch rows per group
#define DS     64        // h-dims per slice
#define TPB    768       // 12 waves
#define OUT_T  256
#define AROW16 528       // u16 per sm16 row (512 data + 16 pad)
#define GHS    200       // ghT row stride in floats
#define OWS    520       // sOutW row stride in u16
#define NK     22        // records per (row, slice): ceil(64/3)
#define NKP    24        // padded record slots

typedef __attribute__((ext_vector_type(8))) short bf8;
typedef __attribute__((ext_vector_type(4))) float f4;
typedef unsigned long long u64;
typedef unsigned short u16;

// .bss scratch: zero at load, not poisoned by the harness.
// Record u64 = [seq16 | bf16 d0 | bf16 d1 | bf16 d2] — single-copy atomic:
// seq and data always consistent. Producers fire-and-forget.
// Exchange is agent-scope atomics ONLY.
// LEDGER (do not retry):
//  - R8/R10 + R3: ANY per-lane load in a spin loop floods the MALL
//    (R3: +16MB FETCH, 816us steady, 31.6ms outlier spiral). Detection must
//    be ONE coalesced address; payload fetch strictly after detect.
//  - R11 + R1: sc0/L2 same-XCD path reads stale L1 in steady state.
//  - R4: lgkm-only barriers + sched_barrier(0) pins = −4% (m141-style
//    pinning; the vmcnt drains at __syncthreads were already free).
// R5: bulletin board g_board[g] (one 64B line, 8 seq slots). Only wave 0
// polls it (1 coalesced load/iter, all slices at once) -> LDS flag ->
// waves 1-7 fetch+validate. Chip-wide poll streams 1792 -> 256.
__device__ __align__(128) u64 g_ring2[2][GB][8][BT][NKP];  // ~786 KB
__device__ __align__(128) u64 g_lcnt[GB * 8 * 16];         // per-(g,s) launch count
__device__ __align__(128) u64 g_board[GB][16];             // [g][slice] latest seq

__device__ __forceinline__ u16 f2bf(float f) {
    union { float f; unsigned int i; } v; v.f = f;
    unsigned int r = v.i + 0x7fffu + ((v.i >> 16) & 1u);
    return (u16)(r >> 16);
}
__device__ __forceinline__ float sigm(float x) { return 1.f / (1.f + __expf(-x)); }
__device__ __forceinline__ float tanh_(float x) {
    x = fminf(x, 40.f);
    float e = __expf(2.f * x);
    return (e - 1.f) / (e + 1.f);
}
#define ALOAD(p)     __hip_atomic_load((p),      __ATOMIC_RELAXED, __HIP_MEMORY_SCOPE_AGENT)
#define ASTORE(p, v) __hip_atomic_store((p), (v), __ATOMIC_RELAXED, __HIP_MEMORY_SCOPE_AGENT)
#define LDS_ST(p, v) __hip_atomic_store((p), (v), __ATOMIC_RELEASE, __HIP_MEMORY_SCOPE_WORKGROUP)
#define LDS_LD(p)    __hip_atomic_load((p), __ATOMIC_ACQUIRE, __HIP_MEMORY_SCOPE_WORKGROUP)

// Fetch-once + validate + retry stragglers, unpack to sm16. Caller must have
// detected readiness first (board + LDS flag); the validate/retry loop only
// handles visibility stragglers (short-lived, same as R0).
__device__ __forceinline__ void fetch_slice(const u64* rb, u16 want, u16* sm,
                                            int j, int lane) {
    const int row = lane >> 3, k = lane & 7;
    const u64* p0 = rb + row * NKP + k;
    const bool v2 = (k + 16) < NK;
    u64 r0 = ALOAD(p0), r1 = ALOAD(p0 + 8), r2 = v2 ? ALOAD(p0 + 16) : 0;
    bool ok0 = ((u16)r0 == want), ok1 = ((u16)r1 == want),
         ok2 = (!v2) || ((u16)r2 == want);
    long guard = 0;
    while (!__all(ok0 && ok1 && ok2) && guard < (1L << 18)) {
        if (!ok0) { r0 = ALOAD(p0);      ok0 = ((u16)r0 == want); }
        if (!ok1) { r1 = ALOAD(p0 + 8);  ok1 = ((u16)r1 == want); }
        if (!ok2) { r2 = ALOAD(p0 + 16); ok2 = ((u16)r2 == want); }
        ++guard;
    }
    u16* dst = sm + row * AROW16 + j * 64;
    int db = 3 * k;
    dst[db] = (u16)(r0 >> 16); dst[db + 1] = (u16)(r0 >> 32); dst[db + 2] = (u16)(r0 >> 48);
    db = 3 * (k + 8);
    dst[db] = (u16)(r1 >> 16); dst[db + 1] = (u16)(r1 >> 32); dst[db + 2] = (u16)(r1 >> 48);
    if (v2) {
        db = 3 * (k + 16);
        dst[db] = (u16)(r2 >> 16);
        if (db + 1 < DS) dst[db + 1] = (u16)(r2 >> 32);
        if (db + 2 < DS) dst[db + 2] = (u16)(r2 >> 48);
    }
}

// Persistent fused GRU+projection. 256 blocks = 32 batch-groups x 8 d-slices.
// Per step: wave 0 stages own slice + polls the group board (1 line) ->
// LDS flag; waves 1-7 wait on the flag then fetch one remote slice each;
// all 12 waves gate GEMM (16 MFMA, 2 chains) vs resident w_hh fragments;
// waves 0-7 gate math (1 dim/lane) -> shfl-pack -> fire-and-forget publish
// (+ wave 7 stores the board seq); waves 8-11 projection vs LDS-resident
// bf16 out_w (1-in-8 steps per block).
// base = lc*512 + 1 (seq never 0 -> virgin .bss can't validate; stale board
// can't match: want - stale = 256+t mod 2^16 != 0).
__global__ __launch_bounds__(TPB, 3) void gru_fused(
    const float* __restrict__ z,    // [256][128]
    const float* __restrict__ hpw,  // [512][128]
    const float* __restrict__ hpb,  // [512]
    const float* __restrict__ whh,  // [1536][512]
    const float* __restrict__ bih,  // [1536]
    const float* __restrict__ bhh,  // [1536]
    const float* __restrict__ outw, // [55][512]
    const float* __restrict__ outb, // [55]
    float* __restrict__ out)        // [256][256][55] fp32
{
    const int blk  = blockIdx.x;
    const int g    = blk & (GB - 1);
    const int s    = blk >> 5;
    const int d0   = s * DS;
    const int row0 = g * BT;
    const int tid  = threadIdx.x;
    const int wave = tid >> 6;
    const int lane = tid & 63;
    const int quad = lane >> 4;
    const int nl   = lane & 15;

    __shared__ __align__(16) u16 sm16[BT * AROW16];   // staged h(t-1) bf16
    __shared__ __align__(16) float ghT[BT][GHS];      // [batch][gate*64+dim]
    __shared__ float bias_r[DS], bias_z[DS], gin_[DS], bhn_[DS];
    __shared__ __align__(16) u16 sOutW[ENC * OWS];    // bf16 out_w, padded
    __shared__ float sOutB[64];
    __shared__ u64 sh_lc;
    __shared__ int sReady;

    u64* lc_own = g_lcnt + (u64)(g * 8 + s) * 16;
    if (tid == 0) { sh_lc = ALOAD(lc_own); sReady = 0; }

    if (tid < DS) {
        int dg = d0 + tid;
        bias_r[tid] = bih[dg]       + bhh[dg];
        bias_z[tid] = bih[512 + dg] + bhh[512 + dg];
        gin_[tid]   = bih[1024 + dg];
        bhn_[tid]   = bhh[1024 + dg];
    }
    if (tid < ENC) sOutB[tid] = outb[tid];
    for (int i = tid; i < ENC * DM; i += TPB)
        sOutW[(i >> 9) * OWS + (i & 511)] = f2bf(outw[i]);

    // Resident w_hh B-fragments: this wave's 16 gate rows x K=512.
    const int gl   = wave * 16 + nl;
    const int sel  = gl >> 6;
    const int jrow = sel * 512 + d0 + (gl & 63);
    bf8 bfrag[16];
#pragma unroll
    for (int kb = 0; kb < 16; ++kb) {
        const float* wp = whh + jrow * DM + kb * 32 + quad * 8;
        bf8 v;
#pragma unroll
        for (int j = 0; j < 8; ++j) v[j] = (short)f2bf(wp[j]);
        bfrag[kb] = v;
    }
    __syncthreads();  // sh_lc, sReady, biases, sOutW ready

    const u64 base = sh_lc * 512ULL + 1ULL;   // seq never 0 (virgin .bss)
    float hprev_reg = 0.f;                    // waves 0-7: h[row=wave][dim=lane]

    // h0 = tanh(z @ hpw^T + hpb): wave w lane d computes its own element
    if (wave < BT) {
        float acc = hpb[d0 + lane];
        const float* zr = z + (row0 + wave) * LAT;
        const float* wr = hpw + (d0 + lane) * LAT;
#pragma unroll 8
        for (int k = 0; k < LAT; ++k) acc += zr[k] * wr[k];
        hprev_reg = tanh_(acc);
        // shfl-pack: record r carries dims 3r,3r+1,3r+2 (out-of-range shfl
        // sources wrap; consumer never unpacks those bytes: db+1/db+2 < DS)
        int hbf = (int)f2bf(hprev_reg);
        int b0 = __shfl(hbf, 3 * lane);
        int b1 = __shfl(hbf, 3 * lane + 1);
        int b2 = __shfl(hbf, 3 * lane + 2);
        if (lane < NK) {
            u64 rec = (u64)(u16)base | ((u64)(u16)b0 << 16)
                    | ((u64)(u16)b1 << 32) | ((u64)(u16)b2 << 48);
            ASTORE(&g_ring2[0][g][s][wave][lane], rec);
        }
        if (wave == 7 && lane == 0)
            ASTORE(&g_board[g][s], (u64)(u16)base);
    }

    const u16* afrag_base = sm16 + (nl & 7) * AROW16;

    for (int t = 1; t <= WIN_; ++t) {
        const int sp = (t - 1) & 1, sc = t & 1;
        const u16 want = (u16)(base + t - 1);

        // ---- stage h(t-1) into sm16 ----
        if (wave < BT)
            sm16[wave * AROW16 + d0 + lane] = f2bf(hprev_reg);  // own slice
        if (wave == 0) {
            // detect-all: poll the group's board line (ONE coalesced load)
            const u64* bp = &g_board[g][lane & 7];
            long guard = 0;
            bool ok;
            do {
                u64 v = ALOAD(bp);
                ok = (lane >= 8) || ((lane & 7) == s) || ((u16)v == want);
            } while (!__all(ok) && ++guard < (1L << 18));
            if (lane == 0) LDS_ST(&sReady, t);
        } else if (wave < 8) {
            long guard = 0;
            while (LDS_LD(&sReady) < t && guard < (1L << 20)) ++guard;
            const int j = (s + wave) & 7;
            fetch_slice(&g_ring2[sp][g][j][0][0], want, sm16, j, lane);
        }
        __syncthreads();  // A: tile complete

        // ---- gate GEMM: 192 rows x K=512, two independent MFMA chains ----
        f4 acc0 = {0.f, 0.f, 0.f, 0.f}, acc1 = {0.f, 0.f, 0.f, 0.f};
#pragma unroll
        for (int kb = 0; kb < 16; kb += 2) {
            bf8 av0 = *(const bf8*)(afrag_base + quad * 8 + kb * 32);
            bf8 av1 = *(const bf8*)(afrag_base + quad * 8 + (kb + 1) * 32);
            acc0 = __builtin_amdgcn_mfma_f32_16x16x32_bf16(av0, bfrag[kb],     acc0, 0, 0, 0);
            acc1 = __builtin_amdgcn_mfma_f32_16x16x32_bf16(av1, bfrag[kb + 1], acc1, 0, 0, 0);
        }
        if (quad < 2) {
            f4 acc = acc0 + acc1;
#pragma unroll
            for (int r = 0; r < 4; ++r) ghT[quad * 4 + r][gl] = acc[r];
        }
        __syncthreads();  // B: ghT complete

        // ---- waves 0-7: gate update (1 dim/lane) + publish ----
        if (wave < BT) {
            const int d = lane;
            const float* grow = &ghT[wave][0];
            float rr = sigm(bias_r[d] + grow[d]);
            float zg = sigm(bias_z[d] + grow[64 + d]);
            float nn = tanh_(gin_[d] + rr * (bhn_[d] + grow[128 + d]));
            float h  = (1.f - zg) * nn + zg * hprev_reg;
            hprev_reg = h;
            int hbf = (int)f2bf(h);
            int b0 = __shfl(hbf, 3 * lane);
            int b1 = __shfl(hbf, 3 * lane + 1);
            int b2 = __shfl(hbf, 3 * lane + 2);
            if (lane < NK) {
                u64 rec = (u64)(u16)(base + t) | ((u64)(u16)b0 << 16)
                        | ((u64)(u16)b1 << 32) | ((u64)(u16)b2 << 48);
                ASTORE(&g_ring2[sc][g][s][wave][lane], rec);
            }
            if (wave == 7 && lane == 0)
                ASTORE(&g_board[g][s], (u64)(u16)(base + t));
        }

        // ---- waves 8-11: projection out[:,tau,:] from sm16 (h(tau+1)=h(t-1)) ----
        const int tau = t - 2;
        const bool proj = (tau >= 0) && ((tau & 7) == s);
        if (proj && wave >= 8) {
            const int e  = (wave - 8) * 16 + nl;
            const int ec = (e < ENC) ? e : (ENC - 1);
            const u16* wrow = sOutW + ec * OWS + quad * 8;
            f4 accp = {0.f, 0.f, 0.f, 0.f};
#pragma unroll
            for (int kb = 0; kb < 16; ++kb) {
                bf8 av = *(const bf8*)(afrag_base + quad * 8 + kb * 32);
                bf8 wv = *(const bf8*)(wrow + kb * 32);
                accp = __builtin_amdgcn_mfma_f32_16x16x32_bf16(av, wv, accp, 0, 0, 0);
            }
            if (quad < 2 && e < ENC) {
                float ob = sOutB[e];
#pragma unroll
                for (int r = 0; r < 4; ++r) {
                    int m = quad * 4 + r;
                    out[(row0 + m) * (OUT_T * ENC) + tau * ENC + e] = accp[r] + ob;
                }
            }
        }
        if (proj) __syncthreads();  // C: protect sm16 before next stage overwrite
    }

    // ---- tail: tau=255 uses h(256) (slot 0, seq base+256); s==7 projects ----
    if (s == 7) {
        const u16 want = (u16)(base + WIN_);
        if (wave < BT)
            sm16[wave * AROW16 + d0 + lane] = f2bf(hprev_reg);
        if (wave == 0) {
            const u64* bp = &g_board[g][lane & 7];
            long guard = 0;
            bool ok;
            do {
                u64 v = ALOAD(bp);
                ok = (lane >= 8) || ((lane & 7) == s) || ((u16)v == want);
            } while (!__all(ok) && ++guard < (1L << 18));
            if (lane == 0) LDS_ST(&sReady, WIN_ + 1);
        } else if (wave < 8) {
            long guard = 0;
            while (LDS_LD(&sReady) < WIN_ + 1 && guard < (1L << 20)) ++guard;
            const int j = (s + wave) & 7;
            fetch_slice(&g_ring2[0][g][j][0][0], want, sm16, j, lane);
        }
        __syncthreads();
        if (wave >= 8) {
            const int e  = (wave - 8) * 16 + nl;
            const int ec = (e < ENC) ? e : (ENC - 1);
            const u16* wrow = sOutW + ec * OWS + quad * 8;
            f4 accp = {0.f, 0.f, 0.f, 0.f};
#pragma unroll
            for (int kb = 0; kb < 16; ++kb) {
                bf8 av = *(const bf8*)(afrag_base + quad * 8 + kb * 32);
                bf8 wv = *(const bf8*)(wrow + kb * 32);
                accp = __builtin_amdgcn_mfma_f32_16x16x32_bf16(av, wv, accp, 0, 0, 0);
            }
            if (quad < 2 && e < ENC) {
                float ob = sOutB[e];
#pragma unroll
                for (int r = 0; r < 4; ++r) {
                    int m = quad * 4 + r;
                    out[(row0 + m) * (OUT_T * ENC) + 255 * ENC + e] = accp[r] + ob;
                }
            }
        }
    }

    // bump own launch counter (next launch's base)
    if (tid == 0) ASTORE(lc_own, sh_lc + 1ULL);
}

extern "C" void kernel_launch(void* const* d_in, const int* in_sizes, int n_in,
                              void* d_out, int out_size, void* d_ws, size_t ws_size,
                              hipStream_t stream) {
    const float* z    = (const float*)d_in[0];
    const float* hpw  = (const float*)d_in[1];
    const float* hpb  = (const float*)d_in[2];
    // d_in[3] = w_ih: unused by the reference (input gates are pure biases)
    const float* whh  = (const float*)d_in[4];
    const float* bih  = (const float*)d_in[5];
    const float* bhh  = (const float*)d_in[6];
    const float* outw = (const float*)d_in[7];
    const float* outb = (const float*)d_in[8];
    float* out = (float*)d_out;

    (void)d_ws; (void)ws_size;  // scratch lives in module .bss
    gru_fused<<<dim3(256), dim3(TPB), 0, stream>>>(
        z, hpw, hpb, whh, bih, bhh, outw, outb, out);
}

// Round 6
// 774.444 us; speedup vs baseline: 47.6634x; 47.6634x over previous
//
#include <hip/hip_runtime.h>

#define DM     512
#define LAT    128
#define WIN_   256
#define ENC    55
#define GB     32        // batch groups
#define BT     8         // batch rows per group
#define DS     64        // h-dims per slice
#define TPB    768       // 12 waves
#define OUT_T  256
#define AROW16 528       // u16 per sm16 row (512 data + 16 pad)
#define GHS    200       // ghT row stride in floats
#define OWS    520       // sOutW row stride in u16
#define NK     22        // records per (row, slice): ceil(64/3)
#define NKP    24        // padded record slots

typedef __attribute__((ext_vector_type(8))) short bf8;
typedef __attribute__((ext_vector_type(4))) float f4;
typedef unsigned long long u64;
typedef unsigned short u16;

// .bss scratch: zero at load, not poisoned by the harness.
// Record u64 = [seq16 | bf16 d0 | bf16 d1 | bf16 d2] — single-copy atomic:
// seq and data always consistent. Producers fire-and-forget.
// Exchange is agent-scope atomics ONLY.
// LEDGER (do not retry):
//  - R8/R10 + R3: ANY per-lane load in a spin loop floods the MALL
//    (R3: +16MB FETCH, 816us steady, 31.6ms outlier spiral). Detection must
//    be ONE coalesced address; payload fetch strictly after detect.
//  - R11 + R1: sc0/L2 same-XCD path reads stale L1 in steady state.
//  - R4: lgkm-only barriers + sched_barrier(0) pins = −4% (m141-style).
//  - R5: equality-ALL poll on a single-slot board livelocks: members skew
//    by 1 step, fast remotes overwrite base+t-1 with base+t before slow
//    remotes post; same-address store merging can hide intermediates.
//    Board seq is MONOTONIC -> poll with wraparound >= ((u16)(v-want)<0x8000),
//    latched per lane. Ring records stay equality-checked (2-parity slots
//    can't skip: producer needs consumer's t before overwriting t-1).
// R6: board g_board[g] (one 64B line, 8 seq slots); only wave 0 polls
// (1 coalesced load/iter covers all 7 remotes) -> LDS flag -> waves 1-7
// fetch+validate. Chip-wide poll streams 1792 -> 256.
__device__ __align__(128) u64 g_ring2[2][GB][8][BT][NKP];  // ~786 KB
__device__ __align__(128) u64 g_lcnt[GB * 8 * 16];         // per-(g,s) launch count
__device__ __align__(128) u64 g_board[GB][16];             // [g][slice] latest seq

__device__ __forceinline__ u16 f2bf(float f) {
    union { float f; unsigned int i; } v; v.f = f;
    unsigned int r = v.i + 0x7fffu + ((v.i >> 16) & 1u);
    return (u16)(r >> 16);
}
__device__ __forceinline__ float sigm(float x) { return 1.f / (1.f + __expf(-x)); }
__device__ __forceinline__ float tanh_(float x) {
    x = fminf(x, 40.f);
    float e = __expf(2.f * x);
    return (e - 1.f) / (e + 1.f);
}
#define ALOAD(p)     __hip_atomic_load((p),      __ATOMIC_RELAXED, __HIP_MEMORY_SCOPE_AGENT)
#define ASTORE(p, v) __hip_atomic_store((p), (v), __ATOMIC_RELAXED, __HIP_MEMORY_SCOPE_AGENT)
#define LDS_ST(p, v) __hip_atomic_store((p), (v), __ATOMIC_RELEASE, __HIP_MEMORY_SCOPE_WORKGROUP)
#define LDS_LD(p)    __hip_atomic_load((p), __ATOMIC_ACQUIRE, __HIP_MEMORY_SCOPE_WORKGROUP)

// Monotonic wraparound readiness: board seq v has reached (or passed) want.
__device__ __forceinline__ bool seq_ge(u16 v, u16 want) {
    return (u16)(v - want) < 0x8000u;
}

// Fetch-once + validate + retry stragglers, unpack to sm16. Caller must have
// detected readiness first (board -> LDS flag); the validate/retry loop only
// handles short-lived visibility stragglers (proven R0 structure).
__device__ __forceinline__ void fetch_slice(const u64* rb, u16 want, u16* sm,
                                            int j, int lane) {
    const int row = lane >> 3, k = lane & 7;
    const u64* p0 = rb + row * NKP + k;
    const bool v2 = (k + 16) < NK;
    u64 r0 = ALOAD(p0), r1 = ALOAD(p0 + 8), r2 = v2 ? ALOAD(p0 + 16) : 0;
    bool ok0 = ((u16)r0 == want), ok1 = ((u16)r1 == want),
         ok2 = (!v2) || ((u16)r2 == want);
    long guard = 0;
    while (!__all(ok0 && ok1 && ok2) && guard < (1L << 18)) {
        if (!ok0) { r0 = ALOAD(p0);      ok0 = ((u16)r0 == want); }
        if (!ok1) { r1 = ALOAD(p0 + 8);  ok1 = ((u16)r1 == want); }
        if (!ok2) { r2 = ALOAD(p0 + 16); ok2 = ((u16)r2 == want); }
        ++guard;
    }
    u16* dst = sm + row * AROW16 + j * 64;
    int db = 3 * k;
    dst[db] = (u16)(r0 >> 16); dst[db + 1] = (u16)(r0 >> 32); dst[db + 2] = (u16)(r0 >> 48);
    db = 3 * (k + 8);
    dst[db] = (u16)(r1 >> 16); dst[db + 1] = (u16)(r1 >> 32); dst[db + 2] = (u16)(r1 >> 48);
    if (v2) {
        db = 3 * (k + 16);
        dst[db] = (u16)(r2 >> 16);
        if (db + 1 < DS) dst[db + 1] = (u16)(r2 >> 32);
        if (db + 2 < DS) dst[db + 2] = (u16)(r2 >> 48);
    }
}

// Persistent fused GRU+projection. 256 blocks = 32 batch-groups x 8 d-slices.
// Per step: wave 0 stages own slice + polls the group board (1 line,
// monotonic >=) -> LDS flag; waves 1-7 wait on flag then fetch one remote
// slice each; all 12 waves gate GEMM (16 MFMA, 2 chains) vs resident w_hh
// fragments; waves 0-7 gate math (1 dim/lane) -> shfl-pack -> fire-and-
// forget publish (+ wave 7 posts board seq); waves 8-11 projection vs
// LDS-resident bf16 out_w (1-in-8 steps per block).
// base = lc*512 + 1 (seq never 0; stale/virgin board values are >=0x8000
// behind want -> never ready; cross-launch skew 512 >> in-launch skew 1).
__global__ __launch_bounds__(TPB, 3) void gru_fused(
    const float* __restrict__ z,    // [256][128]
    const float* __restrict__ hpw,  // [512][128]
    const float* __restrict__ hpb,  // [512]
    const float* __restrict__ whh,  // [1536][512]
    const float* __restrict__ bih,  // [1536]
    const float* __restrict__ bhh,  // [1536]
    const float* __restrict__ outw, // [55][512]
    const float* __restrict__ outb, // [55]
    float* __restrict__ out)        // [256][256][55] fp32
{
    const int blk  = blockIdx.x;
    const int g    = blk & (GB - 1);
    const int s    = blk >> 5;
    const int d0   = s * DS;
    const int row0 = g * BT;
    const int tid  = threadIdx.x;
    const int wave = tid >> 6;
    const int lane = tid & 63;
    const int quad = lane >> 4;
    const int nl   = lane & 15;

    __shared__ __align__(16) u16 sm16[BT * AROW16];   // staged h(t-1) bf16
    __shared__ __align__(16) float ghT[BT][GHS];      // [batch][gate*64+dim]
    __shared__ float bias_r[DS], bias_z[DS], gin_[DS], bhn_[DS];
    __shared__ __align__(16) u16 sOutW[ENC * OWS];    // bf16 out_w, padded
    __shared__ float sOutB[64];
    __shared__ u64 sh_lc;
    __shared__ int sReady;

    u64* lc_own = g_lcnt + (u64)(g * 8 + s) * 16;
    if (tid == 0) { sh_lc = ALOAD(lc_own); sReady = 0; }

    if (tid < DS) {
        int dg = d0 + tid;
        bias_r[tid] = bih[dg]       + bhh[dg];
        bias_z[tid] = bih[512 + dg] + bhh[512 + dg];
        gin_[tid]   = bih[1024 + dg];
        bhn_[tid]   = bhh[1024 + dg];
    }
    if (tid < ENC) sOutB[tid] = outb[tid];
    for (int i = tid; i < ENC * DM; i += TPB)
        sOutW[(i >> 9) * OWS + (i & 511)] = f2bf(outw[i]);

    // Resident w_hh B-fragments: this wave's 16 gate rows x K=512.
    const int gl   = wave * 16 + nl;
    const int sel  = gl >> 6;
    const int jrow = sel * 512 + d0 + (gl & 63);
    bf8 bfrag[16];
#pragma unroll
    for (int kb = 0; kb < 16; ++kb) {
        const float* wp = whh + jrow * DM + kb * 32 + quad * 8;
        bf8 v;
#pragma unroll
        for (int j = 0; j < 8; ++j) v[j] = (short)f2bf(wp[j]);
        bfrag[kb] = v;
    }
    __syncthreads();  // sh_lc, sReady, biases, sOutW ready

    const u64 base = sh_lc * 512ULL + 1ULL;   // seq never 0 (virgin .bss)
    float hprev_reg = 0.f;                    // waves 0-7: h[row=wave][dim=lane]

    // h0 = tanh(z @ hpw^T + hpb): wave w lane d computes its own element
    if (wave < BT) {
        float acc = hpb[d0 + lane];
        const float* zr = z + (row0 + wave) * LAT;
        const float* wr = hpw + (d0 + lane) * LAT;
#pragma unroll 8
        for (int k = 0; k < LAT; ++k) acc += zr[k] * wr[k];
        hprev_reg = tanh_(acc);
        // shfl-pack: record r carries dims 3r,3r+1,3r+2 (out-of-range shfl
        // sources wrap; consumer never unpacks those bytes: db+1/db+2 < DS)
        int hbf = (int)f2bf(hprev_reg);
        int b0 = __shfl(hbf, 3 * lane);
        int b1 = __shfl(hbf, 3 * lane + 1);
        int b2 = __shfl(hbf, 3 * lane + 2);
        if (lane < NK) {
            u64 rec = (u64)(u16)base | ((u64)(u16)b0 << 16)
                    | ((u64)(u16)b1 << 32) | ((u64)(u16)b2 << 48);
            ASTORE(&g_ring2[0][g][s][wave][lane], rec);
        }
        if (wave == 7 && lane == 0)
            ASTORE(&g_board[g][s], (u64)(u16)base);
    }

    const u16* afrag_base = sm16 + (nl & 7) * AROW16;

    for (int t = 1; t <= WIN_; ++t) {
        const int sp = (t - 1) & 1, sc = t & 1;
        const u16 want = (u16)(base + t - 1);

        // ---- stage h(t-1) into sm16 ----
        if (wave < BT)
            sm16[wave * AROW16 + d0 + lane] = f2bf(hprev_reg);  // own slice
        if (wave == 0) {
            // detect-all: ONE coalesced board-line load; latched monotonic >=
            const u64* bp = &g_board[g][lane & 7];
            bool ok = (lane >= 8) || ((lane & 7) == s);
            long guard = 0;
            while (!__all(ok) && guard < (1L << 18)) {
                u64 v = ALOAD(bp);
                ok = ok || seq_ge((u16)v, want);
                ++guard;
            }
            if (lane == 0) LDS_ST(&sReady, t);
        } else if (wave < 8) {
            long guard = 0;
            while (LDS_LD(&sReady) < t && guard < (1L << 20)) ++guard;
            const int j = (s + wave) & 7;
            fetch_slice(&g_ring2[sp][g][j][0][0], want, sm16, j, lane);
        }
        __syncthreads();  // A: tile complete

        // ---- gate GEMM: 192 rows x K=512, two independent MFMA chains ----
        f4 acc0 = {0.f, 0.f, 0.f, 0.f}, acc1 = {0.f, 0.f, 0.f, 0.f};
#pragma unroll
        for (int kb = 0; kb < 16; kb += 2) {
            bf8 av0 = *(const bf8*)(afrag_base + quad * 8 + kb * 32);
            bf8 av1 = *(const bf8*)(afrag_base + quad * 8 + (kb + 1) * 32);
            acc0 = __builtin_amdgcn_mfma_f32_16x16x32_bf16(av0, bfrag[kb],     acc0, 0, 0, 0);
            acc1 = __builtin_amdgcn_mfma_f32_16x16x32_bf16(av1, bfrag[kb + 1], acc1, 0, 0, 0);
        }
        if (quad < 2) {
            f4 acc = acc0 + acc1;
#pragma unroll
            for (int r = 0; r < 4; ++r) ghT[quad * 4 + r][gl] = acc[r];
        }
        __syncthreads();  // B: ghT complete

        // ---- waves 0-7: gate update (1 dim/lane) + publish ----
        if (wave < BT) {
            const int d = lane;
            const float* grow = &ghT[wave][0];
            float rr = sigm(bias_r[d] + grow[d]);
            float zg = sigm(bias_z[d] + grow[64 + d]);
            float nn = tanh_(gin_[d] + rr * (bhn_[d] + grow[128 + d]));
            float h  = (1.f - zg) * nn + zg * hprev_reg;
            hprev_reg = h;
            int hbf = (int)f2bf(h);
            int b0 = __shfl(hbf, 3 * lane);
            int b1 = __shfl(hbf, 3 * lane + 1);
            int b2 = __shfl(hbf, 3 * lane + 2);
            if (lane < NK) {
                u64 rec = (u64)(u16)(base + t) | ((u64)(u16)b0 << 16)
                        | ((u64)(u16)b1 << 32) | ((u64)(u16)b2 << 48);
                ASTORE(&g_ring2[sc][g][s][wave][lane], rec);
            }
            if (wave == 7 && lane == 0)
                ASTORE(&g_board[g][s], (u64)(u16)(base + t));
        }

        // ---- waves 8-11: projection out[:,tau,:] from sm16 (h(tau+1)=h(t-1)) ----
        const int tau = t - 2;
        const bool proj = (tau >= 0) && ((tau & 7) == s);
        if (proj && wave >= 8) {
            const int e  = (wave - 8) * 16 + nl;
            const int ec = (e < ENC) ? e : (ENC - 1);
            const u16* wrow = sOutW + ec * OWS + quad * 8;
            f4 accp = {0.f, 0.f, 0.f, 0.f};
#pragma unroll
            for (int kb = 0; kb < 16; ++kb) {
                bf8 av = *(const bf8*)(afrag_base + quad * 8 + kb * 32);
                bf8 wv = *(const bf8*)(wrow + kb * 32);
                accp = __builtin_amdgcn_mfma_f32_16x16x32_bf16(av, wv, accp, 0, 0, 0);
            }
            if (quad < 2 && e < ENC) {
                float ob = sOutB[e];
#pragma unroll
                for (int r = 0; r < 4; ++r) {
                    int m = quad * 4 + r;
                    out[(row0 + m) * (OUT_T * ENC) + tau * ENC + e] = accp[r] + ob;
                }
            }
        }
        if (proj) __syncthreads();  // C: protect sm16 before next stage overwrite
    }

    // ---- tail: tau=255 uses h(256) (slot 0, seq base+256); s==7 projects ----
    if (s == 7) {
        const u16 want = (u16)(base + WIN_);
        if (wave < BT)
            sm16[wave * AROW16 + d0 + lane] = f2bf(hprev_reg);
        if (wave == 0) {
            const u64* bp = &g_board[g][lane & 7];
            bool ok = (lane >= 8) || ((lane & 7) == s);
            long guard = 0;
            while (!__all(ok) && guard < (1L << 18)) {
                u64 v = ALOAD(bp);
                ok = ok || seq_ge((u16)v, want);
                ++guard;
            }
            if (lane == 0) LDS_ST(&sReady, WIN_ + 1);
        } else if (wave < 8) {
            long guard = 0;
            while (LDS_LD(&sReady) < WIN_ + 1 && guard < (1L << 20)) ++guard;
            const int j = (s + wave) & 7;
            fetch_slice(&g_ring2[0][g][j][0][0], want, sm16, j, lane);
        }
        __syncthreads();
        if (wave >= 8) {
            const int e  = (wave - 8) * 16 + nl;
            const int ec = (e < ENC) ? e : (ENC - 1);
            const u16* wrow = sOutW + ec * OWS + quad * 8;
            f4 accp = {0.f, 0.f, 0.f, 0.f};
#pragma unroll
            for (int kb = 0; kb < 16; ++kb) {
                bf8 av = *(const bf8*)(afrag_base + quad * 8 + kb * 32);
                bf8 wv = *(const bf8*)(wrow + kb * 32);
                accp = __builtin_amdgcn_mfma_f32_16x16x32_bf16(av, wv, accp, 0, 0, 0);
            }
            if (quad < 2 && e < ENC) {
                float ob = sOutB[e];
#pragma unroll
                for (int r = 0; r < 4; ++r) {
                    int m = quad * 4 + r;
                    out[(row0 + m) * (OUT_T * ENC) + 255 * ENC + e] = accp[r] + ob;
                }
            }
        }
    }

    // bump own launch counter (next launch's base)
    if (tid == 0) ASTORE(lc_own, sh_lc + 1ULL);
}

extern "C" void kernel_launch(void* const* d_in, const int* in_sizes, int n_in,
                              void* d_out, int out_size, void* d_ws, size_t ws_size,
                              hipStream_t stream) {
    const float* z    = (const float*)d_in[0];
    const float* hpw  = (const float*)d_in[1];
    const float* hpb  = (const float*)d_in[2];
    // d_in[3] = w_ih: unused by the reference (input gates are pure biases)
    const float* whh  = (const float*)d_in[4];
    const float* bih  = (const float*)d_in[5];
    const float* bhh  = (const float*)d_in[6];
    const float* outw = (const float*)d_in[7];
    const float* outb = (const float*)d_in[8];
    float* out = (float*)d_out;

    (void)d_ws; (void)ws_size;  // scratch lives in module .bss
    gru_fused<<<dim3(256), dim3(TPB), 0, stream>>>(
        z, hpw, hpb, whh, bih, bhh, outw, outb, out);
}

// Round 7
// 729.925 us; speedup vs baseline: 50.5704x; 1.0610x over previous
//
#include <hip/hip_runtime.h>

#define DM     512
#define LAT    128
#define WIN_   256
#define ENC    55
#define GB     32        // batch groups
#define BT     8         // batch rows per group
#define DS     64        // h-dims per slice
#define TPB    768       // 12 waves
#define OUT_T  256
#define AROW16 528       // u16 per sm16 row (512 data + 16 pad)
#define GHS    200       // ghT row stride in floats
#define OWS    520       // sOutW row stride in u16
#define NK     22        // records per (row, slice): ceil(64/3)
#define NKP    24        // padded record slots

typedef __attribute__((ext_vector_type(8))) short bf8;
typedef __attribute__((ext_vector_type(4))) float f4;
typedef unsigned long long u64;
typedef unsigned short u16;

// .bss scratch: zero at load, not poisoned by the harness.
// Record u64 = [seq16 | bf16 d0 | bf16 d1 | bf16 d2] — single-copy atomic:
// seq and data always consistent. Producers fire-and-forget. Consumers poll
// ONE broadcast line per remote (per-wave, decentralized), then fetch-once +
// validate + retry stragglers.
// LEDGER (do not retry):
//  - R8/R10 + R3: ANY per-lane load inside a spin loop floods the MALL
//    (R3: +16MB FETCH, 816us steady, 31.6ms outlier spiral). Detection must
//    be ONE coalesced address; payload fetch strictly after detect.
//  - R11 + R1: sc0/L2 same-XCD fast path reads stale L1 in steady state —
//    probe passes, loop fails. Agent-scope atomics only.
//  - R4: lgkm-only barriers + sched_barrier(0) pins = −4% (m141-style
//    pinning; the vmcnt drains at __syncthreads were already free).
//  - R5: equality-ALL poll on a single-slot monotonic board livelocks
//    (members skew by 1 step; store merging hides intermediates).
//  - R6: centralized board detect (wave0 -> LDS flag -> fetch) = +71us vs
//    R0: serializes the 7 per-wave detect+fetch chains behind the slowest
//    remote. Also: poll streams 1792->256 gave ZERO gain -> poll-stream
//    contention is NOT a limiter. Keep detection per-wave and overlapped.
__device__ __align__(128) u64 g_ring2[2][GB][8][BT][NKP];  // ~786 KB
__device__ __align__(128) u64 g_lcnt[GB * 8 * 16];         // per-(g,s) launch count

__device__ __forceinline__ u16 f2bf(float f) {
    union { float f; unsigned int i; } v; v.f = f;
    unsigned int r = v.i + 0x7fffu + ((v.i >> 16) & 1u);
    return (u16)(r >> 16);
}
__device__ __forceinline__ float sigm(float x) { return 1.f / (1.f + __expf(-x)); }
__device__ __forceinline__ float tanh_(float x) {
    x = fminf(x, 40.f);
    float e = __expf(2.f * x);
    return (e - 1.f) / (e + 1.f);
}
#define ALOAD(p)     __hip_atomic_load((p),      __ATOMIC_RELAXED, __HIP_MEMORY_SCOPE_AGENT)
#define ASTORE(p, v) __hip_atomic_store((p), (v), __ATOMIC_RELAXED, __HIP_MEMORY_SCOPE_AGENT)

// Two-phase (PROVEN R0 structure): poll ONE broadcast line, then fetch-once
// + validate + retry stragglers, unpack to sm16.
__device__ __forceinline__ void fetch_slice(const u64* rb, u16 want, u16* sm,
                                            int j, int lane) {
    const int row = lane >> 3, k = lane & 7;
    {   // cheap poll: one wave-coalesced broadcast address (late-issued rec)
        const u64* pp = rb + 7 * NKP + 21;
        long guard = 0;
        while ((u16)ALOAD(pp) != want && guard < (1L << 18)) ++guard;
    }
    const u64* p0 = rb + row * NKP + k;
    const bool v2 = (k + 16) < NK;
    u64 r0 = ALOAD(p0), r1 = ALOAD(p0 + 8), r2 = v2 ? ALOAD(p0 + 16) : 0;
    bool ok0 = ((u16)r0 == want), ok1 = ((u16)r1 == want),
         ok2 = (!v2) || ((u16)r2 == want);
    long guard = 0;
    while (!__all(ok0 && ok1 && ok2) && guard < (1L << 18)) {
        if (!ok0) { r0 = ALOAD(p0);      ok0 = ((u16)r0 == want); }
        if (!ok1) { r1 = ALOAD(p0 + 8);  ok1 = ((u16)r1 == want); }
        if (!ok2) { r2 = ALOAD(p0 + 16); ok2 = ((u16)r2 == want); }
        ++guard;
    }
    u16* dst = sm + row * AROW16 + j * 64;
    int db = 3 * k;
    dst[db] = (u16)(r0 >> 16); dst[db + 1] = (u16)(r0 >> 32); dst[db + 2] = (u16)(r0 >> 48);
    db = 3 * (k + 8);
    dst[db] = (u16)(r1 >> 16); dst[db + 1] = (u16)(r1 >> 32); dst[db + 2] = (u16)(r1 >> 48);
    if (v2) {
        db = 3 * (k + 16);
        dst[db] = (u16)(r2 >> 16);
        if (db + 1 < DS) dst[db + 1] = (u16)(r2 >> 32);
        if (db + 2 < DS) dst[db + 2] = (u16)(r2 >> 48);
    }
}

// Persistent fused GRU+projection. 256 blocks = 32 batch-groups x 8 d-slices.
// Per step: waves 0-7 stage own slice + poll/fetch one remote slice; all 12
// waves gate GEMM (16 MFMA, 2 indep chains) vs resident w_hh fragments;
// waves 0-7 gate math (1 dim/lane) -> shfl-pack -> fire-and-forget publish;
// waves 8-11 projection vs LDS-resident bf16 out_w (1-in-8 steps per block).
// base = lc*512 + 1 (seq never 0 -> virgin .bss can't validate; no aliasing).
__global__ __launch_bounds__(TPB, 3) void gru_fused(
    const float* __restrict__ z,    // [256][128]
    const float* __restrict__ hpw,  // [512][128]
    const float* __restrict__ hpb,  // [512]
    const float* __restrict__ whh,  // [1536][512]
    const float* __restrict__ bih,  // [1536]
    const float* __restrict__ bhh,  // [1536]
    const float* __restrict__ outw, // [55][512]
    const float* __restrict__ outb, // [55]
    float* __restrict__ out)        // [256][256][55] fp32
{
    const int blk  = blockIdx.x;
    const int g    = blk & (GB - 1);
    const int s    = blk >> 5;
    const int d0   = s * DS;
    const int row0 = g * BT;
    const int tid  = threadIdx.x;
    const int wave = tid >> 6;
    const int lane = tid & 63;
    const int quad = lane >> 4;
    const int nl   = lane & 15;

    __shared__ __align__(16) u16 sm16[BT * AROW16];   // staged h(t-1) bf16
    __shared__ __align__(16) float ghT[BT][GHS];      // [batch][gate*64+dim]
    __shared__ float bias_r[DS], bias_z[DS], gin_[DS], bhn_[DS];
    __shared__ __align__(16) u16 sOutW[ENC * OWS];    // bf16 out_w, padded
    __shared__ float sOutB[64];
    __shared__ u64 sh_lc;

    u64* lc_own = g_lcnt + (u64)(g * 8 + s) * 16;
    if (tid == 0) sh_lc = ALOAD(lc_own);

    if (tid < DS) {
        int dg = d0 + tid;
        bias_r[tid] = bih[dg]       + bhh[dg];
        bias_z[tid] = bih[512 + dg] + bhh[512 + dg];
        gin_[tid]   = bih[1024 + dg];
        bhn_[tid]   = bhh[1024 + dg];
    }
    if (tid < ENC) sOutB[tid] = outb[tid];
    for (int i = tid; i < ENC * DM; i += TPB)
        sOutW[(i >> 9) * OWS + (i & 511)] = f2bf(outw[i]);

    // Resident w_hh B-fragments: this wave's 16 gate rows x K=512.
    const int gl   = wave * 16 + nl;
    const int sel  = gl >> 6;
    const int jrow = sel * 512 + d0 + (gl & 63);
    bf8 bfrag[16];
#pragma unroll
    for (int kb = 0; kb < 16; ++kb) {
        const float* wp = whh + jrow * DM + kb * 32 + quad * 8;
        bf8 v;
#pragma unroll
        for (int j = 0; j < 8; ++j) v[j] = (short)f2bf(wp[j]);
        bfrag[kb] = v;
    }
    __syncthreads();  // sh_lc, biases, sOutW ready

    const u64 base = sh_lc * 512ULL + 1ULL;   // seq never 0 (virgin .bss)
    float hprev_reg = 0.f;                    // waves 0-7: h[row=wave][dim=lane]

    // h0 = tanh(z @ hpw^T + hpb): wave w lane d computes its own element
    if (wave < BT) {
        float acc = hpb[d0 + lane];
        const float* zr = z + (row0 + wave) * LAT;
        const float* wr = hpw + (d0 + lane) * LAT;
#pragma unroll 8
        for (int k = 0; k < LAT; ++k) acc += zr[k] * wr[k];
        hprev_reg = tanh_(acc);
        // shfl-pack: record r carries dims 3r,3r+1,3r+2 (r=21's tail shfl
        // wraps to lane 0/1; consumer never unpacks those: db+1/db+2 < DS)
        int hbf = (int)f2bf(hprev_reg);
        int b0 = __shfl(hbf, 3 * lane);
        int b1 = __shfl(hbf, 3 * lane + 1);
        int b2 = __shfl(hbf, 3 * lane + 2);
        if (lane < NK) {
            u64 rec = (u64)(u16)base | ((u64)(u16)b0 << 16)
                    | ((u64)(u16)b1 << 32) | ((u64)(u16)b2 << 48);
            ASTORE(&g_ring2[0][g][s][wave][lane], rec);
        }
    }

    const u16* afrag_base = sm16 + (nl & 7) * AROW16;

    for (int t = 1; t <= WIN_; ++t) {
        const int sp = (t - 1) & 1, sc = t & 1;
        const u16 want = (u16)(base + t - 1);

        // ---- stage h(t-1) into sm16 ----
        if (wave < BT)
            sm16[wave * AROW16 + d0 + lane] = f2bf(hprev_reg);  // own slice
        if (wave >= 1 && wave < 8) {
            const int j = (s + wave) & 7;
            fetch_slice(&g_ring2[sp][g][j][0][0], want, sm16, j, lane);
        }
        __syncthreads();  // A: tile complete

        // ---- gate GEMM: 192 rows x K=512, two independent MFMA chains ----
        f4 acc0 = {0.f, 0.f, 0.f, 0.f}, acc1 = {0.f, 0.f, 0.f, 0.f};
#pragma unroll
        for (int kb = 0; kb < 16; kb += 2) {
            bf8 av0 = *(const bf8*)(afrag_base + quad * 8 + kb * 32);
            bf8 av1 = *(const bf8*)(afrag_base + quad * 8 + (kb + 1) * 32);
            acc0 = __builtin_amdgcn_mfma_f32_16x16x32_bf16(av0, bfrag[kb],     acc0, 0, 0, 0);
            acc1 = __builtin_amdgcn_mfma_f32_16x16x32_bf16(av1, bfrag[kb + 1], acc1, 0, 0, 0);
        }
        if (quad < 2) {
            f4 acc = acc0 + acc1;
#pragma unroll
            for (int r = 0; r < 4; ++r) ghT[quad * 4 + r][gl] = acc[r];
        }
        __syncthreads();  // B: ghT complete

        // ---- waves 0-7: gate update (1 dim/lane) + publish ----
        if (wave < BT) {
            const int d = lane;
            const float* grow = &ghT[wave][0];
            float rr = sigm(bias_r[d] + grow[d]);
            float zg = sigm(bias_z[d] + grow[64 + d]);
            float nn = tanh_(gin_[d] + rr * (bhn_[d] + grow[128 + d]));
            float h  = (1.f - zg) * nn + zg * hprev_reg;
            hprev_reg = h;
            int hbf = (int)f2bf(h);
            int b0 = __shfl(hbf, 3 * lane);
            int b1 = __shfl(hbf, 3 * lane + 1);
            int b2 = __shfl(hbf, 3 * lane + 2);
            if (lane < NK) {
                u64 rec = (u64)(u16)(base + t) | ((u64)(u16)b0 << 16)
                        | ((u64)(u16)b1 << 32) | ((u64)(u16)b2 << 48);
                ASTORE(&g_ring2[sc][g][s][wave][lane], rec);
            }
        }

        // ---- waves 8-11: projection out[:,tau,:] from sm16 (h(tau+1)=h(t-1)) ----
        const int tau = t - 2;
        const bool proj = (tau >= 0) && ((tau & 7) == s);
        if (proj && wave >= 8) {
            const int e  = (wave - 8) * 16 + nl;
            const int ec = (e < ENC) ? e : (ENC - 1);
            const u16* wrow = sOutW + ec * OWS + quad * 8;
            f4 accp = {0.f, 0.f, 0.f, 0.f};
#pragma unroll
            for (int kb = 0; kb < 16; ++kb) {
                bf8 av = *(const bf8*)(afrag_base + quad * 8 + kb * 32);
                bf8 wv = *(const bf8*)(wrow + kb * 32);
                accp = __builtin_amdgcn_mfma_f32_16x16x32_bf16(av, wv, accp, 0, 0, 0);
            }
            if (quad < 2 && e < ENC) {
                float ob = sOutB[e];
#pragma unroll
                for (int r = 0; r < 4; ++r) {
                    int m = quad * 4 + r;
                    out[(row0 + m) * (OUT_T * ENC) + tau * ENC + e] = accp[r] + ob;
                }
            }
        }
        if (proj) __syncthreads();  // C: protect sm16 before next stage overwrite
    }

    // ---- tail: tau=255 uses h(256) (slot 0, seq base+256); s==7 projects ----
    if (s == 7) {
        const u16 want = (u16)(base + WIN_);
        if (wave < BT)
            sm16[wave * AROW16 + d0 + lane] = f2bf(hprev_reg);
        if (wave >= 1 && wave < 8) {
            const int j = (s + wave) & 7;
            fetch_slice(&g_ring2[0][g][j][0][0], want, sm16, j, lane);
        }
        __syncthreads();
        if (wave >= 8) {
            const int e  = (wave - 8) * 16 + nl;
            const int ec = (e < ENC) ? e : (ENC - 1);
            const u16* wrow = sOutW + ec * OWS + quad * 8;
            f4 accp = {0.f, 0.f, 0.f, 0.f};
#pragma unroll
            for (int kb = 0; kb < 16; ++kb) {
                bf8 av = *(const bf8*)(afrag_base + quad * 8 + kb * 32);
                bf8 wv = *(const bf8*)(wrow + kb * 32);
                accp = __builtin_amdgcn_mfma_f32_16x16x32_bf16(av, wv, accp, 0, 0, 0);
            }
            if (quad < 2 && e < ENC) {
                float ob = sOutB[e];
#pragma unroll
                for (int r = 0; r < 4; ++r) {
                    int m = quad * 4 + r;
                    out[(row0 + m) * (OUT_T * ENC) + 255 * ENC + e] = accp[r] + ob;
                }
            }
        }
    }

    // bump own launch counter (next launch's base)
    if (tid == 0) ASTORE(lc_own, sh_lc + 1ULL);
}

extern "C" void kernel_launch(void* const* d_in, const int* in_sizes, int n_in,
                              void* d_out, int out_size, void* d_ws, size_t ws_size,
                              hipStream_t stream) {
    const float* z    = (const float*)d_in[0];
    const float* hpw  = (const float*)d_in[1];
    const float* hpb  = (const float*)d_in[2];
    // d_in[3] = w_ih: unused by the reference (input gates are pure biases)
    const float* whh  = (const float*)d_in[4];
    const float* bih  = (const float*)d_in[5];
    const float* bhh  = (const float*)d_in[6];
    const float* outw = (const float*)d_in[7];
    const float* outb = (const float*)d_in[8];
    float* out = (float*)d_out;

    (void)d_ws; (void)ws_size;  // scratch lives in module .bss
    gru_fused<<<dim3(256), dim3(TPB), 0, stream>>>(
        z, hpw, hpb, whh, bih, bhh, outw, outb, out);
}

// Round 8
// 717.183 us; speedup vs baseline: 51.4689x; 1.0178x over previous
//
#include <hip/hip_runtime.h>

#define DM     512
#define LAT    128
#define WIN_   256
#define ENC    55
#define GB     32        // batch groups
#define BT     8         // batch rows per group
#define DS     64        // h-dims per slice
#define TPB    768       // 12 waves
#define OUT_T  256
#define AROW16 528       // u16 per sm16 row (512 data + 16 pad)
#define GHS    200       // ghT row stride in floats
#define OWS    520       // sOutW row stride in u16
#define NK     22        // records per (row, slice): ceil(64/3)
#define NKP    24        // padded record slots

typedef __attribute__((ext_vector_type(8))) short bf8;
typedef __attribute__((ext_vector_type(4))) float f4;
typedef unsigned long long u64;
typedef unsigned short u16;

// .bss scratch: zero at load, not poisoned by the harness.
// Record u64 = [seq16 | bf16 d0 | bf16 d1 | bf16 d2] — single-copy atomic:
// seq and data always consistent. Producers fire-and-forget. Consumers poll
// ONE broadcast line per remote (per-wave, decentralized), then fetch-once +
// validate + retry stragglers. (R0 proven protocol — do not touch.)
// LEDGER (do not retry):
//  - R8/R10 + R3: ANY per-lane load inside a spin loop floods the MALL
//    (R3: +16MB FETCH, 816us steady, 31.6ms spiral). Detection = ONE
//    coalesced address; payload fetch strictly after detect.
//  - R11 + R1: sc0/L2 same-XCD fast path reads stale data in steady state.
//  - R4: lgkm-only barriers + sched_barrier(0) pins: neutral-to-negative.
//  - R5: equality-ALL poll on single-slot monotonic board livelocks.
//  - R6: centralized board detect serializes the 7 detect+fetch chains
//    (+71us); poll-stream count (1792 vs 256) is NOT a limiter.
//  - R7: shfl-pack + dual MFMA chains = +28us vs R0 (two independent runs:
//    R4 682, R7 683 vs R0 655). ds_bpermute on the publish path and
//    scheduling perturbation. Reverted — hpack LDS + single chain.
// R8: projection de-barriered. Projection steps snapshot staged h into
// pbuf; waves 8-11 read pbuf, so barrier C is gone and the projection
// overhang (staggered across group members = every step on the group
// critical path) hides under the next step's stage+poll slack.
__device__ __align__(128) u64 g_ring2[2][GB][8][BT][NKP];  // ~786 KB
__device__ __align__(128) u64 g_lcnt[GB * 8 * 16];         // per-(g,s) launch count

__device__ __forceinline__ u16 f2bf(float f) {
    union { float f; unsigned int i; } v; v.f = f;
    unsigned int r = v.i + 0x7fffu + ((v.i >> 16) & 1u);
    return (u16)(r >> 16);
}
__device__ __forceinline__ float sigm(float x) { return 1.f / (1.f + __expf(-x)); }
__device__ __forceinline__ float tanh_(float x) {
    x = fminf(x, 40.f);
    float e = __expf(2.f * x);
    return (e - 1.f) / (e + 1.f);
}
#define ALOAD(p)     __hip_atomic_load((p),      __ATOMIC_RELAXED, __HIP_MEMORY_SCOPE_AGENT)
#define ASTORE(p, v) __hip_atomic_store((p), (v), __ATOMIC_RELAXED, __HIP_MEMORY_SCOPE_AGENT)

// Two-phase (PROVEN R0): poll ONE broadcast line, then fetch-once +
// validate + retry stragglers, unpack to sm16 (and pbuf when DUP).
template <bool DUP>
__device__ __forceinline__ void fetch_slice(const u64* rb, u16 want, u16* sm,
                                            u16* sm2, int j, int lane) {
    const int row = lane >> 3, k = lane & 7;
    {   // cheap poll: one wave-coalesced broadcast address (late-issued rec)
        const u64* pp = rb + 7 * NKP + 21;
        long guard = 0;
        while ((u16)ALOAD(pp) != want && guard < (1L << 18)) ++guard;
    }
    const u64* p0 = rb + row * NKP + k;
    const bool v2 = (k + 16) < NK;
    u64 r0 = ALOAD(p0), r1 = ALOAD(p0 + 8), r2 = v2 ? ALOAD(p0 + 16) : 0;
    bool ok0 = ((u16)r0 == want), ok1 = ((u16)r1 == want),
         ok2 = (!v2) || ((u16)r2 == want);
    long guard = 0;
    while (!__all(ok0 && ok1 && ok2) && guard < (1L << 18)) {
        if (!ok0) { r0 = ALOAD(p0);      ok0 = ((u16)r0 == want); }
        if (!ok1) { r1 = ALOAD(p0 + 8);  ok1 = ((u16)r1 == want); }
        if (!ok2) { r2 = ALOAD(p0 + 16); ok2 = ((u16)r2 == want); }
        ++guard;
    }
    u16* dst  = sm  + row * AROW16 + j * 64;
    u16* dst2 = sm2 + row * AROW16 + j * 64;
    int db = 3 * k;
    dst[db] = (u16)(r0 >> 16); dst[db + 1] = (u16)(r0 >> 32); dst[db + 2] = (u16)(r0 >> 48);
    if (DUP) { dst2[db] = (u16)(r0 >> 16); dst2[db + 1] = (u16)(r0 >> 32); dst2[db + 2] = (u16)(r0 >> 48); }
    db = 3 * (k + 8);
    dst[db] = (u16)(r1 >> 16); dst[db + 1] = (u16)(r1 >> 32); dst[db + 2] = (u16)(r1 >> 48);
    if (DUP) { dst2[db] = (u16)(r1 >> 16); dst2[db + 1] = (u16)(r1 >> 32); dst2[db + 2] = (u16)(r1 >> 48); }
    if (v2) {
        db = 3 * (k + 16);
        dst[db] = (u16)(r2 >> 16);
        if (DUP) dst2[db] = (u16)(r2 >> 16);
        if (db + 1 < DS) { dst[db + 1] = (u16)(r2 >> 32); if (DUP) dst2[db + 1] = (u16)(r2 >> 32); }
        if (db + 2 < DS) { dst[db + 2] = (u16)(r2 >> 48); if (DUP) dst2[db + 2] = (u16)(r2 >> 48); }
    }
}

// Persistent fused GRU+projection. 256 blocks = 32 batch-groups x 8 d-slices.
// Per step: waves 0-7 stage own slice + poll/fetch one remote slice (dup
// into pbuf on projection steps); all 12 waves gate GEMM (16 MFMA) vs
// resident w_hh fragments; waves 0-7 gate math (1 dim/lane) -> pack records
// via LDS -> fire-and-forget publish; waves 8-11 projection vs LDS-resident
// bf16 out_w reading the pbuf snapshot (no trailing barrier — overlaps the
// next step's stage+poll).
// base = lc*512 + 1 (seq never 0 -> virgin .bss can't validate; no aliasing).
__global__ __launch_bounds__(TPB, 3) void gru_fused(
    const float* __restrict__ z,    // [256][128]
    const float* __restrict__ hpw,  // [512][128]
    const float* __restrict__ hpb,  // [512]
    const float* __restrict__ whh,  // [1536][512]
    const float* __restrict__ bih,  // [1536]
    const float* __restrict__ bhh,  // [1536]
    const float* __restrict__ outw, // [55][512]
    const float* __restrict__ outb, // [55]
    float* __restrict__ out)        // [256][256][55] fp32
{
    const int blk  = blockIdx.x;
    const int g    = blk & (GB - 1);
    const int s    = blk >> 5;
    const int d0   = s * DS;
    const int row0 = g * BT;
    const int tid  = threadIdx.x;
    const int wave = tid >> 6;
    const int lane = tid & 63;
    const int quad = lane >> 4;
    const int nl   = lane & 15;

    __shared__ __align__(16) u16 sm16[BT * AROW16];   // staged h(t-1) bf16
    __shared__ __align__(16) u16 pbuf[BT * AROW16];   // projection snapshot
    __shared__ __align__(16) float ghT[BT][GHS];      // [batch][gate*64+dim]
    __shared__ float bias_r[DS], bias_z[DS], gin_[DS], bhn_[DS];
    __shared__ __align__(16) u16 hpack[BT][66];       // bf16 h(t) rows + pad
    __shared__ __align__(16) u16 sOutW[ENC * OWS];    // bf16 out_w, padded
    __shared__ float sOutB[64];
    __shared__ u64 sh_lc;

    u64* lc_own = g_lcnt + (u64)(g * 8 + s) * 16;
    if (tid == 0) sh_lc = ALOAD(lc_own);

    if (tid < DS) {
        int dg = d0 + tid;
        bias_r[tid] = bih[dg]       + bhh[dg];
        bias_z[tid] = bih[512 + dg] + bhh[512 + dg];
        gin_[tid]   = bih[1024 + dg];
        bhn_[tid]   = bhh[1024 + dg];
    }
    if (tid < ENC) sOutB[tid] = outb[tid];
    for (int i = tid; i < ENC * DM; i += TPB)
        sOutW[(i >> 9) * OWS + (i & 511)] = f2bf(outw[i]);

    // Resident w_hh B-fragments: this wave's 16 gate rows x K=512.
    const int gl   = wave * 16 + nl;
    const int sel  = gl >> 6;
    const int jrow = sel * 512 + d0 + (gl & 63);
    bf8 bfrag[16];
#pragma unroll
    for (int kb = 0; kb < 16; ++kb) {
        const float* wp = whh + jrow * DM + kb * 32 + quad * 8;
        bf8 v;
#pragma unroll
        for (int j = 0; j < 8; ++j) v[j] = (short)f2bf(wp[j]);
        bfrag[kb] = v;
    }
    __syncthreads();  // sh_lc, biases, sOutW ready

    const u64 base = sh_lc * 512ULL + 1ULL;   // seq never 0 (virgin .bss)
    float hprev_reg = 0.f;                    // waves 0-7: h[row=wave][dim=lane]

    // h0 = tanh(z @ hpw^T + hpb): wave w lane d computes its own element
    if (wave < BT) {
        float acc = hpb[d0 + lane];
        const float* zr = z + (row0 + wave) * LAT;
        const float* wr = hpw + (d0 + lane) * LAT;
#pragma unroll 8
        for (int k = 0; k < LAT; ++k) acc += zr[k] * wr[k];
        hprev_reg = tanh_(acc);
        if (lane < 2) hpack[wave][64 + lane] = 0;   // zero record pads once
        hpack[wave][lane] = f2bf(hprev_reg);
        const u16 sq = (u16)base;
        if (lane < NK) {
            u16 b0 = hpack[wave][3 * lane], b1 = hpack[wave][3 * lane + 1],
                b2 = hpack[wave][3 * lane + 2];
            u64 rec = (u64)sq | ((u64)b0 << 16) | ((u64)b1 << 32) | ((u64)b2 << 48);
            ASTORE(&g_ring2[0][g][s][wave][lane], rec);
        }
    }

    const u16* afrag_base = sm16 + (nl & 7) * AROW16;
    const u16* pfrag_base = pbuf + (nl & 7) * AROW16;

    for (int t = 1; t <= WIN_; ++t) {
        const int sp = (t - 1) & 1, sc = t & 1;
        const u16 want = (u16)(base + t - 1);
        const int tau  = t - 2;
        const bool proj = (tau >= 0) && ((tau & 7) == s);

        // ---- stage h(t-1) into sm16 (+ pbuf snapshot on proj steps) ----
        if (wave < BT) {
            u16 hb = f2bf(hprev_reg);
            sm16[wave * AROW16 + d0 + lane] = hb;   // own slice
            if (proj) pbuf[wave * AROW16 + d0 + lane] = hb;
        }
        if (wave >= 1 && wave < 8) {
            const int j = (s + wave) & 7;
            if (proj) fetch_slice<true >(&g_ring2[sp][g][j][0][0], want, sm16, pbuf, j, lane);
            else      fetch_slice<false>(&g_ring2[sp][g][j][0][0], want, sm16, pbuf, j, lane);
        }
        __syncthreads();  // A: tile complete

        // ---- gate GEMM: 192 rows x K=512 ----
        f4 acc = {0.f, 0.f, 0.f, 0.f};
#pragma unroll
        for (int kb = 0; kb < 16; ++kb) {
            bf8 av = *(const bf8*)(afrag_base + quad * 8 + kb * 32);
            acc = __builtin_amdgcn_mfma_f32_16x16x32_bf16(av, bfrag[kb], acc, 0, 0, 0);
        }
        if (quad < 2) {
#pragma unroll
            for (int r = 0; r < 4; ++r) ghT[quad * 4 + r][gl] = acc[r];
        }
        __syncthreads();  // B: ghT complete

        // ---- waves 0-7: gate update (1 dim/lane) + publish ----
        if (wave < BT) {
            const int d = lane;
            const float* grow = &ghT[wave][0];
            float rr = sigm(bias_r[d] + grow[d]);
            float zg = sigm(bias_z[d] + grow[64 + d]);
            float nn = tanh_(gin_[d] + rr * (bhn_[d] + grow[128 + d]));
            float h  = (1.f - zg) * nn + zg * hprev_reg;
            hprev_reg = h;
            hpack[wave][d] = f2bf(h);
            const u16 sq = (u16)(base + t);
            if (lane < NK) {   // same-wave LDS write->read: lgkmcnt-ordered
                u16 b0 = hpack[wave][3 * lane], b1 = hpack[wave][3 * lane + 1],
                    b2 = hpack[wave][3 * lane + 2];
                u64 rec = (u64)sq | ((u64)b0 << 16) | ((u64)b1 << 32) | ((u64)b2 << 48);
                ASTORE(&g_ring2[sc][g][s][wave][lane], rec);
            }
        }

        // ---- waves 8-11: projection out[:,tau,:] from pbuf (h(tau+1)) ----
        // No trailing barrier: pbuf is rewritten 8 steps later, and waves
        // 8-11 pass barrier A(t+1) only after finishing — overlaps the next
        // step's stage+poll instead of blocking publish.
        if (proj && wave >= 8) {
            const int e  = (wave - 8) * 16 + nl;
            const int ec = (e < ENC) ? e : (ENC - 1);
            const u16* wrow = sOutW + ec * OWS + quad * 8;
            f4 accp = {0.f, 0.f, 0.f, 0.f};
#pragma unroll
            for (int kb = 0; kb < 16; ++kb) {
                bf8 av = *(const bf8*)(pfrag_base + quad * 8 + kb * 32);
                bf8 wv = *(const bf8*)(wrow + kb * 32);
                accp = __builtin_amdgcn_mfma_f32_16x16x32_bf16(av, wv, accp, 0, 0, 0);
            }
            if (quad < 2 && e < ENC) {
                float ob = sOutB[e];
#pragma unroll
                for (int r = 0; r < 4; ++r) {
                    int m = quad * 4 + r;
                    out[(row0 + m) * (OUT_T * ENC) + tau * ENC + e] = accp[r] + ob;
                }
            }
        }
    }

    // ---- tail: tau=255 uses h(256) (slot 0, seq base+256); s==7 projects ----
    if (s == 7) {
        const u16 want = (u16)(base + WIN_);
        if (wave < BT)
            sm16[wave * AROW16 + d0 + lane] = f2bf(hprev_reg);
        if (wave >= 1 && wave < 8) {
            const int j = (s + wave) & 7;
            fetch_slice<false>(&g_ring2[0][g][j][0][0], want, sm16, pbuf, j, lane);
        }
        __syncthreads();
        if (wave >= 8) {
            const int e  = (wave - 8) * 16 + nl;
            const int ec = (e < ENC) ? e : (ENC - 1);
            const u16* wrow = sOutW + ec * OWS + quad * 8;
            f4 accp = {0.f, 0.f, 0.f, 0.f};
#pragma unroll
            for (int kb = 0; kb < 16; ++kb) {
                bf8 av = *(const bf8*)(afrag_base + quad * 8 + kb * 32);
                bf8 wv = *(const bf8*)(wrow + kb * 32);
                accp = __builtin_amdgcn_mfma_f32_16x16x32_bf16(av, wv, accp, 0, 0, 0);
            }
            if (quad < 2 && e < ENC) {
                float ob = sOutB[e];
#pragma unroll
                for (int r = 0; r < 4; ++r) {
                    int m = quad * 4 + r;
                    out[(row0 + m) * (OUT_T * ENC) + 255 * ENC + e] = accp[r] + ob;
                }
            }
        }
    }

    // bump own launch counter (next launch's base)
    if (tid == 0) ASTORE(lc_own, sh_lc + 1ULL);
}

extern "C" void kernel_launch(void* const* d_in, const int* in_sizes, int n_in,
                              void* d_out, int out_size, void* d_ws, size_t ws_size,
                              hipStream_t stream) {
    const float* z    = (const float*)d_in[0];
    const float* hpw  = (const float*)d_in[1];
    const float* hpb  = (const float*)d_in[2];
    // d_in[3] = w_ih: unused by the reference (input gates are pure biases)
    const float* whh  = (const float*)d_in[4];
    const float* bih  = (const float*)d_in[5];
    const float* bhh  = (const float*)d_in[6];
    const float* outw = (const float*)d_in[7];
    const float* outb = (const float*)d_in[8];
    float* out = (float*)d_out;

    (void)d_ws; (void)ws_size;  // scratch lives in module .bss
    gru_fused<<<dim3(256), dim3(TPB), 0, stream>>>(
        z, hpw, hpb, whh, bih, bhh, outw, outb, out);
}